// Round 13
// baseline (162.640 us; speedup 1.0000x reference)
//
#include <hip/hip_runtime.h>

// InteractionBlock (ViT-Adapter injector+extractor with MSDeformAttn) for MI355X.
// R13: big GEMMs -> BM=256,BN=128, 8 waves of 64x64 (LDS re-read traffic -33%,
// was the binding resource). 72KB dynamic LDS, 3-buffer counted-vmcnt ledger
// (WAITV(3)), setprio on. Mids/samplers/LNs unchanged from R12.

#define LQ_VIT 2304
#define NA_ADA 12096

typedef float f32x4 __attribute__((ext_vector_type(4)));
typedef float f32x8 __attribute__((ext_vector_type(8)));
typedef short bf16x8 __attribute__((ext_vector_type(8)));
typedef unsigned short u16x8 __attribute__((ext_vector_type(8)));

__device__ __forceinline__ unsigned short f2bf(float f) {
  unsigned u = __builtin_bit_cast(unsigned, f);
  u += 0x7FFFu + ((u >> 16) & 1u);   // round-to-nearest-even bf16
  return (unsigned short)(u >> 16);
}
__device__ __forceinline__ float bf2f(unsigned short u) {
  return __builtin_bit_cast(float, (unsigned)u << 16);
}
__device__ __forceinline__ f32x8 ld8bf(const unsigned short* p) {
  u16x8 t = *(const u16x8*)p;
  f32x8 r;
#pragma unroll
  for (int j = 0; j < 8; j++) r[j] = bf2f(t[j]);
  return r;
}

__device__ __forceinline__ void gload_lds16(const void* g, void* l) {
  __builtin_amdgcn_global_load_lds(
      (__attribute__((address_space(1))) void*)(void*)g,
      (__attribute__((address_space(3))) void*)l, 16, 0, 0);
}

#define FENCE() __builtin_amdgcn_sched_barrier(0)
#define WAITV(n) do { asm volatile("s_waitcnt vmcnt(" #n ")" ::: "memory"); } while (0)
#define BAR() do { FENCE(); __builtin_amdgcn_s_barrier(); FENCE(); } while (0)

// ================= fused prep kernel =========================================
struct PrepPack {
  const float* W[8];
  unsigned short* WT[8];
  int N[8];
  int cum[9];
  const float* adapter; unsigned short* adbf; int n4;
  const float* vit; const float* qg; const float* qb; unsigned short* qln;
  const float* isv; const float* iav; const float* ibv;
  const float* esv; const float* eav;
  float* bci; float* bbig;
};

__global__ __launch_bounds__(256) void prep_kernel(PrepPack pp) {
  int b = blockIdx.x;
  int tid = threadIdx.x;
  if (b < 2568) {  // ---- transpose: W[768,N] f32 -> WT[N,768] bf16
    int kb = b / 107, col = b % 107;
    int z = 0;
#pragma unroll
    for (int i = 0; i < 8; i++) if (col >= pp.cum[i + 1]) z = i + 1;
    int nb = col - pp.cum[z];
    const float* __restrict__ W = pp.W[z];
    unsigned short* __restrict__ WT = pp.WT[z];
    int N = pp.N[z];
    int kb32 = kb * 32, nb32 = nb * 32;
    __shared__ float tile[32][33];
    int tx = tid & 31, ty = tid >> 5;
    for (int i = ty; i < 32; i += 8) {
      int n = nb32 + tx;
      tile[i][tx] = (n < N) ? W[(size_t)(kb32 + i) * N + n] : 0.f;
    }
    __syncthreads();
    for (int i = ty; i < 32; i += 8) {
      int n = nb32 + i, k = kb32 + tx;
      if (n < N) WT[(size_t)n * 768 + k] = f2bf(tile[tx][i]);
    }
  } else if (b < 4616) {  // ---- adapter f32 -> bf16
    for (int i = (b - 2568) * 256 + tid; i < pp.n4; i += 2048 * 256) {
      float4 v = ((const float4*)pp.adapter)[i];
      ushort4 o;
      o.x = f2bf(v.x); o.y = f2bf(v.y); o.z = f2bf(v.z); o.w = f2bf(v.w);
      ((ushort4*)pp.adbf)[i] = o;
    }
  } else if (b < 5192) {  // ---- vit LN -> bf16
    int wid = (b - 4616) * 4 + (tid >> 6);
    int lane = tid & 63;
    if (wid >= LQ_VIT) return;
    const float* row = pp.vit + (size_t)wid * 768;
    float x[12]; float s = 0.f;
#pragma unroll
    for (int j = 0; j < 12; j++) { x[j] = row[lane + j * 64]; s += x[j]; }
#pragma unroll
    for (int o = 32; o >= 1; o >>= 1) s += __shfl_xor(s, o);
    float mean = s * (1.f / 768.f);
    float v = 0.f;
#pragma unroll
    for (int j = 0; j < 12; j++) { float d = x[j] - mean; v += d * d; }
#pragma unroll
    for (int o = 32; o >= 1; o >>= 1) v += __shfl_xor(v, o);
    float rs = rsqrtf(v * (1.f / 768.f) + 1e-6f);
#pragma unroll
    for (int j = 0; j < 12; j++) {
      int c = lane + j * 64;
      pp.qln[(size_t)wid * 768 + c] = f2bf((x[j] - mean) * rs * pp.qg[c] + pp.qb[c]);
    }
  } else {  // ---- bias concat
    for (int i = tid; i < 840; i += 256) {
      if (i < 144) pp.bci[i] = pp.isv[i];
      else if (i < 216) pp.bci[i] = pp.iav[i - 144];
      if (i < 768) pp.bbig[i] = pp.ibv[i];
      else if (i < 816) pp.bbig[i] = pp.esv[i - 768];
      else pp.bbig[i] = pp.eav[i - 816];
    }
  }
}

struct GemmTask {
  const unsigned short* A; const unsigned short* BT;
  const float* bias; unsigned short* C;
  int M, N, NT, nwg;
};

// ================= big GEMM: 512 thr, BM=256, BN=128, BK=32, 3-buffer ========
// 8 waves of 64x64 (FM=FN=4): LDS re-read = A 2x + B 4x = 64KB/body for 2x the
// outputs of the 64x32 variant (-33%/output). 3 loads/wave/body -> WAITV(3).
// Dynamic LDS 72KB -> 2 blocks/CU, 16 waves/CU, single-round grids.
__global__ __launch_bounds__(512, 4) void gemm_big256_kernel(GemmTask t0, GemmTask t1,
                                                             int split) {
  extern __shared__ unsigned short lds[];          // 3 x (256+128)*32 shorts
  const int BUF = (256 + 128) * 32;                // 12288 shorts = 24KB

  GemmTask tk = (blockIdx.x < split) ? t0 : t1;
  int id = (blockIdx.x < split) ? blockIdx.x : blockIdx.x - split;
  int nwg = tk.nwg;
  int qq = nwg >> 3, rr = nwg & 7;
  int xcd = id & 7, idx = id >> 3;
  int wg = (xcd < rr ? xcd * (qq + 1) : rr * (qq + 1) + (xcd - rr) * qq) + idx;
  int nt = wg % tk.NT, mt = wg / tk.NT;            // nt-major: A reused across nt
  int m0 = mt * 256, n0 = nt * 128;
  int M = tk.M, N = tk.N;
  const unsigned short* __restrict__ A = tk.A;
  const unsigned short* __restrict__ BT = tk.BT;
  const int K = 768, kT = 24;

  int tid = threadIdx.x;
  int w = tid >> 6, lane = tid & 63;   // 8 waves
  int wr = w >> 1, wc = w & 1;         // wave tile 64 (rows) x 64 (cols)
  int frow = lane & 15, ghi = lane >> 4;
  int sr = lane >> 2;
  int sgx = (((lane & 3) ^ ((lane >> 3) & 3)) * 8);
  int gxr = ((ghi ^ ((frow >> 1) & 3)) * 8);

  f32x4 acc[4][4] = {};

  auto stage = [&](unsigned short* dst, int k0) {
#pragma unroll
    for (int i = 0; i < 3; i++) {
      int c = w * 3 + i;                 // 24 chunks: 16 A (256 rows) + 8 B (128)
      if (c < 16) {
        int gm = m0 + c * 16 + sr; if (gm >= M) gm = M - 1;
        gload_lds16(&A[(size_t)gm * K + k0 + sgx], &dst[c * 512]);
      } else {
        int gn = n0 + (c - 16) * 16 + sr; if (gn >= N) gn = N - 1;
        gload_lds16(&BT[(size_t)gn * K + k0 + sgx], &dst[c * 512]);
      }
    }
  };

  stage(&lds[0], 0);
  stage(&lds[BUF], 32);
  WAITV(3);   // buf0's 3 landed, buf1's 3 flying
  BAR();

#pragma unroll
  for (int t = 0; t < kT; t++) {
    unsigned short* cb = &lds[(t % 3) * BUF];
    if (t + 2 < kT) stage(&lds[((t + 2) % 3) * BUF], (t + 2) << 5);
    const unsigned short* As_ = cb;
    const unsigned short* Bs_ = cb + 256 * 32;
    bf16x8 af[4], bg[4];
#pragma unroll
    for (int m = 0; m < 4; m++)
      af[m] = *(const bf16x8*)&As_[(wr * 64 + m * 16 + frow) * 32 + gxr];
#pragma unroll
    for (int n = 0; n < 4; n++)
      bg[n] = *(const bf16x8*)&Bs_[(wc * 64 + n * 16 + frow) * 32 + gxr];
    __builtin_amdgcn_s_setprio(1);
#pragma unroll
    for (int m = 0; m < 4; m++)
#pragma unroll
      for (int n = 0; n < 4; n++)
        acc[m][n] = __builtin_amdgcn_mfma_f32_16x16x32_bf16(af[m], bg[n], acc[m][n], 0, 0, 0);
    __builtin_amdgcn_s_setprio(0);
    if (t < kT - 1) {
      if (t + 2 < kT) { WAITV(3); }   // retire t+1's; t+2's stay flying
      else            { WAITV(0); }
      BAR();
    }
  }

  int orow = (lane >> 4) * 4, ocol = lane & 15;
  unsigned short* C = tk.C;
  const float* bias = tk.bias;
#pragma unroll
  for (int m = 0; m < 4; m++) {
    int gmb = m0 + wr * 64 + m * 16 + orow;
#pragma unroll
    for (int n = 0; n < 4; n++) {
      int gn = n0 + wc * 64 + n * 16 + ocol;
      if (gn < N) {
        float bv = bias[gn];
#pragma unroll
        for (int r = 0; r < 4; r++) {
          int gm = gmb + r;
          if (gm < M) C[(size_t)gm * N + gn] = f2bf(acc[m][n][r] + bv);
        }
      }
    }
  }
}

// ================= mid GEMM 8-wave: 512 thr, BM=64, BN=128, BK=32, 3-buf =====
__global__ __launch_bounds__(512) void gemm_mid8_kernel(
    const unsigned short* __restrict__ A, const unsigned short* __restrict__ BT,
    const float* __restrict__ bias, unsigned short* __restrict__ C,
    int M, int N, int NT) {
  __shared__ unsigned short lds[3][(64 + 128) * 32];  // 3 x 12KB

  int nwg = gridDim.x;
  int id = blockIdx.x;
  int qq = nwg >> 3, rr = nwg & 7;
  int xcd = id & 7, idx = id >> 3;
  int wg = (xcd < rr ? xcd * (qq + 1) : rr * (qq + 1) + (xcd - rr) * qq) + idx;
  int nt = wg % NT, mt = wg / NT;
  int m0 = mt * 64, n0 = nt * 128;
  const int K = 768, kT = 24;

  int tid = threadIdx.x;
  int w = tid >> 6, lane = tid & 63;   // 8 waves
  int wr = w >> 2, wc = w & 3;         // wave tile 32 x 32
  int frow = lane & 15, ghi = lane >> 4;
  int sr = lane >> 2;
  int sgx = (((lane & 3) ^ ((lane >> 3) & 3)) * 8);
  int gxr = ((ghi ^ ((frow >> 1) & 3)) * 8);
  int wu = __builtin_amdgcn_readfirstlane(w);

  f32x4 acc[2][2] = {};

  auto stage = [&](unsigned short* dst, int k0) {
    {
      int c = w;                        // chunks 0-7 (A: 0-3, B: 4-7)
      if (c < 4) {
        int gm = m0 + c * 16 + sr; if (gm >= M) gm = M - 1;
        gload_lds16(&A[(size_t)gm * K + k0 + sgx], &dst[c * 512]);
      } else {
        int gn = n0 + (c - 4) * 16 + sr; if (gn >= N) gn = N - 1;
        gload_lds16(&BT[(size_t)gn * K + k0 + sgx], &dst[c * 512]);
      }
    }
    if (w < 4) {                        // chunks 8-11 (B cols 64-127)
      int c = 8 + w;
      int gn = n0 + (c - 4) * 16 + sr; if (gn >= N) gn = N - 1;
      gload_lds16(&BT[(size_t)gn * K + k0 + sgx], &dst[c * 512]);
    }
  };

  stage(&lds[0][0], 0);
  stage(&lds[1][0], 32);
  if (wu < 4) { WAITV(2); } else { WAITV(1); }
  BAR();

#pragma unroll
  for (int t = 0; t < kT; t++) {
    unsigned short* cb = &lds[t % 3][0];
    if (t + 2 < kT) stage(&lds[(t + 2) % 3][0], (t + 2) << 5);
    const unsigned short* As_ = cb;
    const unsigned short* Bs_ = cb + 64 * 32;
    bf16x8 af[2], bg[2];
#pragma unroll
    for (int m = 0; m < 2; m++)
      af[m] = *(const bf16x8*)&As_[(wr * 32 + m * 16 + frow) * 32 + gxr];
#pragma unroll
    for (int n = 0; n < 2; n++)
      bg[n] = *(const bf16x8*)&Bs_[(wc * 32 + n * 16 + frow) * 32 + gxr];
#pragma unroll
    for (int m = 0; m < 2; m++)
#pragma unroll
      for (int n = 0; n < 2; n++)
        acc[m][n] = __builtin_amdgcn_mfma_f32_16x16x32_bf16(af[m], bg[n], acc[m][n], 0, 0, 0);
    if (t < kT - 1) {
      if (t + 2 < kT) { if (wu < 4) { WAITV(2); } else { WAITV(1); } }
      else            { WAITV(0); }
      BAR();
    }
  }

  int orow = (lane >> 4) * 4, ocol = lane & 15;
#pragma unroll
  for (int m = 0; m < 2; m++) {
    int gmb = m0 + wr * 32 + m * 16 + orow;
#pragma unroll
    for (int n = 0; n < 2; n++) {
      int gn = n0 + wc * 32 + n * 16 + ocol;
      if (gn < N) {
        float bv = bias[gn];
#pragma unroll
        for (int r = 0; r < 4; r++) {
          int gm = gmb + r;
          if (gm < M) C[(size_t)gm * N + gn] = f2bf(acc[m][n][r] + bv);
        }
      }
    }
  }
}

// ---------------- fused residual + LayerNorm (float4 vectorized) -------------
__global__ __launch_bounds__(256) void residual_ln_kernel(
    const float* __restrict__ vit, const unsigned short* __restrict__ attn,
    const float* __restrict__ gamma, const float* __restrict__ g,
    const float* __restrict__ b, float* __restrict__ vout,
    unsigned short* __restrict__ vln, int R) {
  int wid = blockIdx.x * 4 + (threadIdx.x >> 6);
  int lane = threadIdx.x & 63;
  if (wid >= R) return;
  const float4* ra = (const float4*)(vit + (size_t)wid * 768);
  const ushort4* rb = (const ushort4*)(attn + (size_t)wid * 768);
  float4* vo = (float4*)(vout + (size_t)wid * 768);
  ushort4* vl = (ushort4*)(vln + (size_t)wid * 768);
  float x[12]; float s = 0.f;
#pragma unroll
  for (int j = 0; j < 3; j++) {
    int c4 = lane + j * 64;
    float4 a = ra[c4];
    ushort4 t = rb[c4];
    float4 gm = ((const float4*)gamma)[c4];
    x[j*4+0] = a.x + gm.x * bf2f(t.x);
    x[j*4+1] = a.y + gm.y * bf2f(t.y);
    x[j*4+2] = a.z + gm.z * bf2f(t.z);
    x[j*4+3] = a.w + gm.w * bf2f(t.w);
    float4 o; o.x = x[j*4+0]; o.y = x[j*4+1]; o.z = x[j*4+2]; o.w = x[j*4+3];
    vo[c4] = o;
    s += x[j*4+0] + x[j*4+1] + x[j*4+2] + x[j*4+3];
  }
#pragma unroll
  for (int o = 32; o >= 1; o >>= 1) s += __shfl_xor(s, o);
  float mean = s * (1.f / 768.f);
  float v = 0.f;
#pragma unroll
  for (int j = 0; j < 12; j++) { float d = x[j] - mean; v += d * d; }
#pragma unroll
  for (int o = 32; o >= 1; o >>= 1) v += __shfl_xor(v, o);
  float rs = rsqrtf(v * (1.f / 768.f) + 1e-6f);
#pragma unroll
  for (int j = 0; j < 3; j++) {
    int c4 = lane + j * 64;
    float4 gg = ((const float4*)g)[c4];
    float4 bb = ((const float4*)b)[c4];
    ushort4 o;
    o.x = f2bf((x[j*4+0] - mean) * rs * gg.x + bb.x);
    o.y = f2bf((x[j*4+1] - mean) * rs * gg.y + bb.y);
    o.z = f2bf((x[j*4+2] - mean) * rs * gg.z + bb.z);
    o.w = f2bf((x[j*4+3] - mean) * rs * gg.w + bb.w);
    vl[c4] = o;
  }
}

// ---------------- add + LayerNorm -> f32 out (float4 vectorized) -------------
__global__ __launch_bounds__(256) void add_ln_f32_kernel(
    const float* __restrict__ Xa, const unsigned short* __restrict__ Xb,
    const float* __restrict__ g, const float* __restrict__ b,
    float* __restrict__ out, int R) {
  int wid = blockIdx.x * 4 + (threadIdx.x >> 6);
  int lane = threadIdx.x & 63;
  if (wid >= R) return;
  const float4* ra = (const float4*)(Xa + (size_t)wid * 768);
  const ushort4* rb = (const ushort4*)(Xb + (size_t)wid * 768);
  float4* ro = (float4*)(out + (size_t)wid * 768);
  float x[12]; float s = 0.f;
#pragma unroll
  for (int j = 0; j < 3; j++) {
    int c4 = lane + j * 64;
    float4 a = ra[c4];
    ushort4 t = rb[c4];
    x[j*4+0] = a.x + bf2f(t.x);
    x[j*4+1] = a.y + bf2f(t.y);
    x[j*4+2] = a.z + bf2f(t.z);
    x[j*4+3] = a.w + bf2f(t.w);
    s += x[j*4+0] + x[j*4+1] + x[j*4+2] + x[j*4+3];
  }
#pragma unroll
  for (int o = 32; o >= 1; o >>= 1) s += __shfl_xor(s, o);
  float mean = s * (1.f / 768.f);
  float v = 0.f;
#pragma unroll
  for (int j = 0; j < 12; j++) { float d = x[j] - mean; v += d * d; }
#pragma unroll
  for (int o = 32; o >= 1; o >>= 1) v += __shfl_xor(v, o);
  float rs = rsqrtf(v * (1.f / 768.f) + 1e-6f);
#pragma unroll
  for (int j = 0; j < 3; j++) {
    int c4 = lane + j * 64;
    float4 gg = ((const float4*)g)[c4];
    float4 bb = ((const float4*)b)[c4];
    float4 o;
    o.x = (x[j*4+0] - mean) * rs * gg.x + bb.x;
    o.y = (x[j*4+1] - mean) * rs * gg.y + bb.y;
    o.z = (x[j*4+2] - mean) * rs * gg.z + bb.z;
    o.w = (x[j*4+3] - mean) * rs * gg.w + bb.w;
    ro[c4] = o;
  }
}

// ---------------- deformable samplers: 8 ch/lane, 4 heads/wave ---------------
__global__ __launch_bounds__(256) void sampler_inj_kernel(
    const float* __restrict__ ref, const unsigned short* __restrict__ sa,
    const unsigned short* __restrict__ v, unsigned short* __restrict__ out, int vst) {
  int gw = (blockIdx.x * 256 + threadIdx.x) >> 6;
  int lane = threadIdx.x & 63;
  int qp = gw / 3, wv = gw - qp * 3;
  int gh = wv * 4 + (lane >> 4);
  int q = qp * 2 + (gh >= 6 ? 1 : 0);
  if (q >= LQ_VIT) return;
  int h = gh >= 6 ? gh - 6 : gh;
  int c = h * 128 + (lane & 15) * 8;
  float rx = ref[q * 2], ry = ref[q * 2 + 1];
  const unsigned short* row = sa + (size_t)q * 216;
  float lg[12]; float mx = -1e30f;
#pragma unroll
  for (int i = 0; i < 12; i++) { lg[i] = bf2f(row[144 + h * 12 + i]); mx = fmaxf(mx, lg[i]); }
  float s = 0.f;
#pragma unroll
  for (int i = 0; i < 12; i++) { lg[i] = __expf(lg[i] - mx); s += lg[i]; }
  float inv = 1.f / s;
  f32x8 acc = {};
  const int LW[3] = {96, 48, 24};
  const int LS[3] = {0, 9216, 11520};
#pragma unroll
  for (int l = 0; l < 3; l++) {
    const int Wl = LW[l], st = LS[l], Wm = Wl - 1;
    const float Wf = (float)Wl;
#pragma unroll
    for (int p = 0; p < 4; p++) {
      int ob = ((h * 3 + l) * 4 + p) * 2;
      float ix = fmaf(rx, Wf, bf2f(row[ob])) - 0.5f;
      float iy = fmaf(ry, Wf, bf2f(row[ob + 1])) - 0.5f;
      float x0f = floorf(ix), y0f = floorf(iy);
      float wx = ix - x0f, wy = iy - y0f;
      int x0 = (int)x0f, y0 = (int)y0f;
      float aw = lg[l * 4 + p] * inv;
      float wy0 = (1.f - wy) * aw, wy1 = wy * aw;
      float w00 = (1.f - wx) * wy0, w01 = wx * wy0;
      float w10 = (1.f - wx) * wy1, w11 = wx * wy1;
      bool xv0 = (unsigned)x0 < (unsigned)Wl, xv1 = (unsigned)(x0 + 1) < (unsigned)Wl;
      bool yv0 = (unsigned)y0 < (unsigned)Wl, yv1 = (unsigned)(y0 + 1) < (unsigned)Wl;
      w00 = (xv0 && yv0) ? w00 : 0.f;
      w01 = (xv1 && yv0) ? w01 : 0.f;
      w10 = (xv0 && yv1) ? w10 : 0.f;
      w11 = (xv1 && yv1) ? w11 : 0.f;
      int x0c = min(max(x0, 0), Wm), x1c = min(max(x0 + 1, 0), Wm);
      int y0c = min(max(y0, 0), Wm), y1c = min(max(y0 + 1, 0), Wm);
      const unsigned short* r0 = v + ((size_t)(st + y0c * Wl) * vst + c);
      const unsigned short* r1 = v + ((size_t)(st + y1c * Wl) * vst + c);
      acc += w00 * ld8bf(r0 + (size_t)x0c * vst) + w01 * ld8bf(r0 + (size_t)x1c * vst)
           + w10 * ld8bf(r1 + (size_t)x0c * vst) + w11 * ld8bf(r1 + (size_t)x1c * vst);
    }
  }
  u16x8 o8;
#pragma unroll
  for (int j = 0; j < 8; j++) o8[j] = f2bf(acc[j]);
  *(u16x8*)&out[(size_t)q * 768 + c] = o8;
}

__global__ __launch_bounds__(256) void sampler_ext_kernel(
    const float* __restrict__ ref, const unsigned short* __restrict__ sa, int sst,
    const unsigned short* __restrict__ v, unsigned short* __restrict__ out) {
  int gw = (blockIdx.x * 256 + threadIdx.x) >> 6;
  int lane = threadIdx.x & 63;
  int qp = gw / 3, wv = gw - qp * 3;
  int gh = wv * 4 + (lane >> 4);
  int q = qp * 2 + (gh >= 6 ? 1 : 0);
  if (q >= NA_ADA) return;
  int h = gh >= 6 ? gh - 6 : gh;
  int c = h * 128 + (lane & 15) * 8;
  float rx = ref[q * 2], ry = ref[q * 2 + 1];
  const unsigned short* row = sa + (size_t)q * sst;
  float lg[4]; float mx = -1e30f;
#pragma unroll
  for (int p = 0; p < 4; p++) { lg[p] = bf2f(row[48 + h * 4 + p]); mx = fmaxf(mx, lg[p]); }
  float s = 0.f;
#pragma unroll
  for (int p = 0; p < 4; p++) { lg[p] = __expf(lg[p] - mx); s += lg[p]; }
  float inv = 1.f / s;
  f32x8 acc = {};
#pragma unroll
  for (int p = 0; p < 4; p++) {
    int ob = (h * 4 + p) * 2;
    float ix = fmaf(rx, 48.f, bf2f(row[ob])) - 0.5f;
    float iy = fmaf(ry, 48.f, bf2f(row[ob + 1])) - 0.5f;
    float x0f = floorf(ix), y0f = floorf(iy);
    float wx = ix - x0f, wy = iy - y0f;
    int x0 = (int)x0f, y0 = (int)y0f;
    float aw = lg[p] * inv;
    float wy0 = (1.f - wy) * aw, wy1 = wy * aw;
    float w00 = (1.f - wx) * wy0, w01 = wx * wy0;
    float w10 = (1.f - wx) * wy1, w11 = wx * wy1;
    bool xv0 = (unsigned)x0 < 48u, xv1 = (unsigned)(x0 + 1) < 48u;
    bool yv0 = (unsigned)y0 < 48u, yv1 = (unsigned)(y0 + 1) < 48u;
    w00 = (xv0 && yv0) ? w00 : 0.f;
    w01 = (xv1 && yv0) ? w01 : 0.f;
    w10 = (xv0 && yv1) ? w10 : 0.f;
    w11 = (xv1 && yv1) ? w11 : 0.f;
    int x0c = min(max(x0, 0), 47), x1c = min(max(x0 + 1, 0), 47);
    int y0c = min(max(y0, 0), 47), y1c = min(max(y0 + 1, 0), 47);
    const unsigned short* r0 = v + ((size_t)(y0c * 48) * 768 + c);
    const unsigned short* r1 = v + ((size_t)(y1c * 48) * 768 + c);
    acc += w00 * ld8bf(r0 + (size_t)x0c * 768) + w01 * ld8bf(r0 + (size_t)x1c * 768)
         + w10 * ld8bf(r1 + (size_t)x0c * 768) + w11 * ld8bf(r1 + (size_t)x1c * 768);
  }
  u16x8 o8;
#pragma unroll
  for (int j = 0; j < 8; j++) o8[j] = f2bf(acc[j]);
  *(u16x8*)&out[(size_t)q * 768 + c] = o8;
}

extern "C" void kernel_launch(void* const* d_in, const int* in_sizes, int n_in,
                              void* d_out, int out_size, void* d_ws, size_t ws_size,
                              hipStream_t stream) {
  (void)in_sizes; (void)n_in; (void)out_size; (void)ws_size;
  const float* vit      = (const float*)d_in[0];
  const float* adapter  = (const float*)d_in[1];
  const float* ref1     = (const float*)d_in[2];
  const float* ref2     = (const float*)d_in[3];
  const float* inj_qn_g = (const float*)d_in[4];
  const float* inj_qn_b = (const float*)d_in[5];
  const float* inj_Wv   = (const float*)d_in[6];
  const float* inj_bv   = (const float*)d_in[7];
  const float* inj_Ws   = (const float*)d_in[8];
  const float* inj_bs   = (const float*)d_in[9];
  const float* inj_Wa   = (const float*)d_in[10];
  const float* inj_ba   = (const float*)d_in[11];
  const float* inj_Wo   = (const float*)d_in[12];
  const float* inj_bo   = (const float*)d_in[13];
  const float* inj_gamma= (const float*)d_in[14];
  const float* ext_vn_g = (const float*)d_in[15];
  const float* ext_vn_b = (const float*)d_in[16];
  const float* ext_qn_g = (const float*)d_in[17];
  const float* ext_qn_b = (const float*)d_in[18];
  const float* ext_Wv   = (const float*)d_in[19];
  const float* ext_bv   = (const float*)d_in[20];
  const float* ext_Ws   = (const float*)d_in[21];
  const float* ext_bs   = (const float*)d_in[22];
  const float* ext_Wa   = (const float*)d_in[23];
  const float* ext_ba   = (const float*)d_in[24];
  const float* ext_Wo   = (const float*)d_in[25];
  const float* ext_bo   = (const float*)d_in[26];

  size_t cur = 0;
  auto take = [&](size_t bytes) {
    void* p = (char*)d_ws + cur;
    cur += (bytes + 255) & ~(size_t)255;
    return p;
  };
  unsigned short* WBIG = (unsigned short*)take((size_t)840 * 768 * 2);
  unsigned short* WTIO = (unsigned short*)take((size_t)768 * 768 * 2);
  unsigned short* WTEV = (unsigned short*)take((size_t)768 * 768 * 2);
  unsigned short* WTEO = (unsigned short*)take((size_t)768 * 768 * 2);
  unsigned short* WSAI = (unsigned short*)take((size_t)216 * 768 * 2);
  float* BCI  = (float*)take((size_t)216 * 4);
  float* BBIG = (float*)take((size_t)840 * 4);
  unsigned short* ADBF = (unsigned short*)take((size_t)NA_ADA * 768 * 2);
  unsigned short* QLN  = (unsigned short*)take((size_t)LQ_VIT * 768 * 2);
  unsigned short* CBIG = (unsigned short*)take((size_t)NA_ADA * 840 * 2);  // [v_inj | sae]
  unsigned short* SAI  = (unsigned short*)take((size_t)LQ_VIT * 216 * 2);
  unsigned short* SAMPI= (unsigned short*)take((size_t)LQ_VIT * 768 * 2);
  unsigned short* ATTNI= (unsigned short*)take((size_t)LQ_VIT * 768 * 2);
  unsigned short* VLN  = (unsigned short*)take((size_t)LQ_VIT * 768 * 2);
  unsigned short* VEXT = (unsigned short*)take((size_t)LQ_VIT * 768 * 2);
  unsigned short* SAMPE = ADBF;   // adapter_bf16 dead after big GEMM 1
  unsigned short* ATTN2 = CBIG;   // CBIG dead after sampler_ext

  float* out_vit = (float*)d_out;
  float* out_ada = out_vit + (size_t)LQ_VIT * 768;

  PrepPack pp;
  pp.W[0] = inj_Wv; pp.WT[0] = WBIG;               pp.N[0] = 768;
  pp.W[1] = ext_Ws; pp.WT[1] = WBIG + 768 * 768;   pp.N[1] = 48;
  pp.W[2] = ext_Wa; pp.WT[2] = WBIG + 816 * 768;   pp.N[2] = 24;
  pp.W[3] = inj_Wo; pp.WT[3] = WTIO;               pp.N[3] = 768;
  pp.W[4] = ext_Wv; pp.WT[4] = WTEV;               pp.N[4] = 768;
  pp.W[5] = ext_Wo; pp.WT[5] = WTEO;               pp.N[5] = 768;
  pp.W[6] = inj_Ws; pp.WT[6] = WSAI;               pp.N[6] = 144;
  pp.W[7] = inj_Wa; pp.WT[7] = WSAI + 144 * 768;   pp.N[7] = 72;
  int cum = 0;
  for (int i = 0; i < 8; i++) { pp.cum[i] = cum; cum += (pp.N[i] + 31) / 32; }
  pp.cum[8] = cum;  // 107
  pp.adapter = adapter; pp.adbf = ADBF; pp.n4 = (NA_ADA * 768) / 4;
  pp.vit = vit; pp.qg = inj_qn_g; pp.qb = inj_qn_b; pp.qln = QLN;
  pp.isv = inj_bs; pp.iav = inj_ba; pp.ibv = inj_bv;
  pp.esv = ext_bs; pp.eav = ext_ba;
  pp.bci = BCI; pp.bbig = BBIG;
  prep_kernel<<<5193, 256, 0, stream>>>(pp);

  const size_t BIG_LDS = (size_t)3 * (256 + 128) * 32 * 2;  // 73728 B

  // launch 2: big GEMM 1 (N=840) packed with SAI (N=216), BM=256
  GemmTask tA, tB;
  tA.A = ADBF; tA.BT = WBIG; tA.bias = BBIG; tA.C = CBIG;
  tA.M = NA_ADA; tA.N = 840; tA.NT = 7; tA.nwg = 48 * 7;   // ceil(12096/256)=48
  tB.A = QLN; tB.BT = WSAI; tB.bias = BCI; tB.C = SAI;
  tB.M = LQ_VIT; tB.N = 216; tB.NT = 2; tB.nwg = 9 * 2;    // 2304/256=9
  gemm_big256_kernel<<<48 * 7 + 9 * 2, 512, BIG_LDS, stream>>>(tA, tB, 48 * 7);

  sampler_inj_kernel<<<864, 256, 0, stream>>>(ref1, SAI, CBIG, SAMPI, 840);

  gemm_mid8_kernel<<<36 * 6, 512, 0, stream>>>(SAMPI, WTIO, inj_bo, ATTNI, LQ_VIT, 768, 6);
  residual_ln_kernel<<<576, 256, 0, stream>>>(vit, ATTNI, inj_gamma, ext_vn_g, ext_vn_b,
                                              out_vit, VLN, LQ_VIT);
  gemm_mid8_kernel<<<36 * 6, 512, 0, stream>>>(VLN, WTEV, ext_bv, VEXT, LQ_VIT, 768, 6);

  sampler_ext_kernel<<<4536, 256, 0, stream>>>(ref2, CBIG + 768, 840, VEXT, SAMPE);

  // big GEMM 2 (N=768), BM=256
  GemmTask tC;
  tC.A = SAMPE; tC.BT = WTEO; tC.bias = ext_bo; tC.C = ATTN2;
  tC.M = NA_ADA; tC.N = 768; tC.NT = 6; tC.nwg = 48 * 6;
  gemm_big256_kernel<<<48 * 6, 512, BIG_LDS, stream>>>(tC, tC, 48 * 6);

  add_ln_f32_kernel<<<3024, 256, 0, stream>>>(adapter, ATTN2, ext_qn_g, ext_qn_b, out_ada, NA_ADA);
}

// Round 14
// 152.472 us; speedup vs baseline: 1.0667x; 1.0667x over previous
//
#include <hip/hip_runtime.h>

// InteractionBlock (ViT-Adapter injector+extractor with MSDeformAttn) for MI355X.
// R14: revert big GEMMs to R12 (BM=128 8-wave, proven best: parallelism >
// LDS-traffic), setprio on both; add_ln reads bf16 adapter copy (-18.6MB).

#define LQ_VIT 2304
#define NA_ADA 12096

typedef float f32x4 __attribute__((ext_vector_type(4)));
typedef float f32x8 __attribute__((ext_vector_type(8)));
typedef short bf16x8 __attribute__((ext_vector_type(8)));
typedef unsigned short u16x8 __attribute__((ext_vector_type(8)));

__device__ __forceinline__ unsigned short f2bf(float f) {
  unsigned u = __builtin_bit_cast(unsigned, f);
  u += 0x7FFFu + ((u >> 16) & 1u);   // round-to-nearest-even bf16
  return (unsigned short)(u >> 16);
}
__device__ __forceinline__ float bf2f(unsigned short u) {
  return __builtin_bit_cast(float, (unsigned)u << 16);
}
__device__ __forceinline__ f32x8 ld8bf(const unsigned short* p) {
  u16x8 t = *(const u16x8*)p;
  f32x8 r;
#pragma unroll
  for (int j = 0; j < 8; j++) r[j] = bf2f(t[j]);
  return r;
}

__device__ __forceinline__ void gload_lds16(const void* g, void* l) {
  __builtin_amdgcn_global_load_lds(
      (__attribute__((address_space(1))) void*)(void*)g,
      (__attribute__((address_space(3))) void*)l, 16, 0, 0);
}

#define FENCE() __builtin_amdgcn_sched_barrier(0)
#define WAITV(n) do { asm volatile("s_waitcnt vmcnt(" #n ")" ::: "memory"); } while (0)
#define BAR() do { FENCE(); __builtin_amdgcn_s_barrier(); FENCE(); } while (0)

// ================= fused prep kernel =========================================
struct PrepPack {
  const float* W[8];
  unsigned short* WT[8];
  int N[8];
  int cum[9];
  const float* adapter; unsigned short* adbf; int n4;
  const float* vit; const float* qg; const float* qb; unsigned short* qln;
  const float* isv; const float* iav; const float* ibv;
  const float* esv; const float* eav;
  float* bci; float* bbig;
};

__global__ __launch_bounds__(256) void prep_kernel(PrepPack pp) {
  int b = blockIdx.x;
  int tid = threadIdx.x;
  if (b < 2568) {  // ---- transpose: W[768,N] f32 -> WT[N,768] bf16
    int kb = b / 107, col = b % 107;
    int z = 0;
#pragma unroll
    for (int i = 0; i < 8; i++) if (col >= pp.cum[i + 1]) z = i + 1;
    int nb = col - pp.cum[z];
    const float* __restrict__ W = pp.W[z];
    unsigned short* __restrict__ WT = pp.WT[z];
    int N = pp.N[z];
    int kb32 = kb * 32, nb32 = nb * 32;
    __shared__ float tile[32][33];
    int tx = tid & 31, ty = tid >> 5;
    for (int i = ty; i < 32; i += 8) {
      int n = nb32 + tx;
      tile[i][tx] = (n < N) ? W[(size_t)(kb32 + i) * N + n] : 0.f;
    }
    __syncthreads();
    for (int i = ty; i < 32; i += 8) {
      int n = nb32 + i, k = kb32 + tx;
      if (n < N) WT[(size_t)n * 768 + k] = f2bf(tile[tx][i]);
    }
  } else if (b < 4616) {  // ---- adapter f32 -> bf16
    for (int i = (b - 2568) * 256 + tid; i < pp.n4; i += 2048 * 256) {
      float4 v = ((const float4*)pp.adapter)[i];
      ushort4 o;
      o.x = f2bf(v.x); o.y = f2bf(v.y); o.z = f2bf(v.z); o.w = f2bf(v.w);
      ((ushort4*)pp.adbf)[i] = o;
    }
  } else if (b < 5192) {  // ---- vit LN -> bf16
    int wid = (b - 4616) * 4 + (tid >> 6);
    int lane = tid & 63;
    if (wid >= LQ_VIT) return;
    const float* row = pp.vit + (size_t)wid * 768;
    float x[12]; float s = 0.f;
#pragma unroll
    for (int j = 0; j < 12; j++) { x[j] = row[lane + j * 64]; s += x[j]; }
#pragma unroll
    for (int o = 32; o >= 1; o >>= 1) s += __shfl_xor(s, o);
    float mean = s * (1.f / 768.f);
    float v = 0.f;
#pragma unroll
    for (int j = 0; j < 12; j++) { float d = x[j] - mean; v += d * d; }
#pragma unroll
    for (int o = 32; o >= 1; o >>= 1) v += __shfl_xor(v, o);
    float rs = rsqrtf(v * (1.f / 768.f) + 1e-6f);
#pragma unroll
    for (int j = 0; j < 12; j++) {
      int c = lane + j * 64;
      pp.qln[(size_t)wid * 768 + c] = f2bf((x[j] - mean) * rs * pp.qg[c] + pp.qb[c]);
    }
  } else {  // ---- bias concat
    for (int i = tid; i < 840; i += 256) {
      if (i < 144) pp.bci[i] = pp.isv[i];
      else if (i < 216) pp.bci[i] = pp.iav[i - 144];
      if (i < 768) pp.bbig[i] = pp.ibv[i];
      else if (i < 816) pp.bbig[i] = pp.esv[i - 768];
      else pp.bbig[i] = pp.eav[i - 816];
    }
  }
}

struct GemmTask {
  const unsigned short* A; const unsigned short* BT;
  const float* bias; unsigned short* C;
  int M, N, NT, nwg;
};

// ================= big GEMM 8-wave: 512 thr, BM=128, BN=128, BK=32, 3-buf ====
__global__ __launch_bounds__(512) void gemm_big8_kernel(GemmTask t0, GemmTask t1,
                                                        int split) {
  __shared__ unsigned short lds[3][(128 + 128) * 32];  // 3 x 16KB

  GemmTask tk = (blockIdx.x < split) ? t0 : t1;
  int id = (blockIdx.x < split) ? blockIdx.x : blockIdx.x - split;
  int nwg = tk.nwg;
  int qq = nwg >> 3, rr = nwg & 7;
  int xcd = id & 7, idx = id >> 3;
  int wg = (xcd < rr ? xcd * (qq + 1) : rr * (qq + 1) + (xcd - rr) * qq) + idx;
  int nt = wg % tk.NT, mt = wg / tk.NT;
  int m0 = mt * 128, n0 = nt * 128;
  int M = tk.M, N = tk.N;
  const unsigned short* __restrict__ A = tk.A;
  const unsigned short* __restrict__ BT = tk.BT;
  const int K = 768, kT = 24;

  int tid = threadIdx.x;
  int w = tid >> 6, lane = tid & 63;   // 8 waves
  int wr = w >> 2, wc = w & 3;         // wave tile 64 x 32
  int frow = lane & 15, ghi = lane >> 4;
  int sr = lane >> 2;
  int sgx = (((lane & 3) ^ ((lane >> 3) & 3)) * 8);
  int gxr = ((ghi ^ ((frow >> 1) & 3)) * 8);

  f32x4 acc[4][2] = {};

  auto stage = [&](unsigned short* dst, int k0) {
#pragma unroll
    for (int i = 0; i < 2; i++) {
      int c = w * 2 + i;                 // 16 chunks: 8 A + 8 B
      if (c < 8) {
        int gm = m0 + c * 16 + sr; if (gm >= M) gm = M - 1;
        gload_lds16(&A[(size_t)gm * K + k0 + sgx], &dst[c * 512]);
      } else {
        int gn = n0 + (c - 8) * 16 + sr; if (gn >= N) gn = N - 1;
        gload_lds16(&BT[(size_t)gn * K + k0 + sgx], &dst[c * 512]);
      }
    }
  };

  stage(&lds[0][0], 0);
  stage(&lds[1][0], 32);
  WAITV(2);
  BAR();

#pragma unroll
  for (int t = 0; t < kT; t++) {
    unsigned short* cb = &lds[t % 3][0];
    if (t + 2 < kT) stage(&lds[(t + 2) % 3][0], (t + 2) << 5);
    const unsigned short* As_ = cb;
    const unsigned short* Bs_ = cb + 128 * 32;
    bf16x8 af[4], bg[2];
#pragma unroll
    for (int m = 0; m < 4; m++)
      af[m] = *(const bf16x8*)&As_[(wr * 64 + m * 16 + frow) * 32 + gxr];
#pragma unroll
    for (int n = 0; n < 2; n++)
      bg[n] = *(const bf16x8*)&Bs_[(wc * 32 + n * 16 + frow) * 32 + gxr];
    __builtin_amdgcn_s_setprio(1);
#pragma unroll
    for (int m = 0; m < 4; m++)
#pragma unroll
      for (int n = 0; n < 2; n++)
        acc[m][n] = __builtin_amdgcn_mfma_f32_16x16x32_bf16(af[m], bg[n], acc[m][n], 0, 0, 0);
    __builtin_amdgcn_s_setprio(0);
    if (t < kT - 1) {
      if (t + 2 < kT) { WAITV(2); }
      else            { WAITV(0); }
      BAR();
    }
  }

  int orow = (lane >> 4) * 4, ocol = lane & 15;
  unsigned short* C = tk.C;
  const float* bias = tk.bias;
#pragma unroll
  for (int m = 0; m < 4; m++) {
    int gmb = m0 + wr * 64 + m * 16 + orow;
#pragma unroll
    for (int n = 0; n < 2; n++) {
      int gn = n0 + wc * 32 + n * 16 + ocol;
      if (gn < N) {
        float bv = bias[gn];
#pragma unroll
        for (int r = 0; r < 4; r++) {
          int gm = gmb + r;
          if (gm < M) C[(size_t)gm * N + gn] = f2bf(acc[m][n][r] + bv);
        }
      }
    }
  }
}

// ================= mid GEMM 8-wave: 512 thr, BM=64, BN=128, BK=32, 3-buf =====
__global__ __launch_bounds__(512) void gemm_mid8_kernel(
    const unsigned short* __restrict__ A, const unsigned short* __restrict__ BT,
    const float* __restrict__ bias, unsigned short* __restrict__ C,
    int M, int N, int NT) {
  __shared__ unsigned short lds[3][(64 + 128) * 32];  // 3 x 12KB

  int nwg = gridDim.x;
  int id = blockIdx.x;
  int qq = nwg >> 3, rr = nwg & 7;
  int xcd = id & 7, idx = id >> 3;
  int wg = (xcd < rr ? xcd * (qq + 1) : rr * (qq + 1) + (xcd - rr) * qq) + idx;
  int nt = wg % NT, mt = wg / NT;
  int m0 = mt * 64, n0 = nt * 128;
  const int K = 768, kT = 24;

  int tid = threadIdx.x;
  int w = tid >> 6, lane = tid & 63;   // 8 waves
  int wr = w >> 2, wc = w & 3;         // wave tile 32 x 32
  int frow = lane & 15, ghi = lane >> 4;
  int sr = lane >> 2;
  int sgx = (((lane & 3) ^ ((lane >> 3) & 3)) * 8);
  int gxr = ((ghi ^ ((frow >> 1) & 3)) * 8);
  int wu = __builtin_amdgcn_readfirstlane(w);

  f32x4 acc[2][2] = {};

  auto stage = [&](unsigned short* dst, int k0) {
    {
      int c = w;                        // chunks 0-7 (A: 0-3, B: 4-7)
      if (c < 4) {
        int gm = m0 + c * 16 + sr; if (gm >= M) gm = M - 1;
        gload_lds16(&A[(size_t)gm * K + k0 + sgx], &dst[c * 512]);
      } else {
        int gn = n0 + (c - 4) * 16 + sr; if (gn >= N) gn = N - 1;
        gload_lds16(&BT[(size_t)gn * K + k0 + sgx], &dst[c * 512]);
      }
    }
    if (w < 4) {                        // chunks 8-11 (B cols 64-127)
      int c = 8 + w;
      int gn = n0 + (c - 4) * 16 + sr; if (gn >= N) gn = N - 1;
      gload_lds16(&BT[(size_t)gn * K + k0 + sgx], &dst[c * 512]);
    }
  };

  stage(&lds[0][0], 0);
  stage(&lds[1][0], 32);
  if (wu < 4) { WAITV(2); } else { WAITV(1); }
  BAR();

#pragma unroll
  for (int t = 0; t < kT; t++) {
    unsigned short* cb = &lds[t % 3][0];
    if (t + 2 < kT) stage(&lds[(t + 2) % 3][0], (t + 2) << 5);
    const unsigned short* As_ = cb;
    const unsigned short* Bs_ = cb + 64 * 32;
    bf16x8 af[2], bg[2];
#pragma unroll
    for (int m = 0; m < 2; m++)
      af[m] = *(const bf16x8*)&As_[(wr * 32 + m * 16 + frow) * 32 + gxr];
#pragma unroll
    for (int n = 0; n < 2; n++)
      bg[n] = *(const bf16x8*)&Bs_[(wc * 32 + n * 16 + frow) * 32 + gxr];
#pragma unroll
    for (int m = 0; m < 2; m++)
#pragma unroll
      for (int n = 0; n < 2; n++)
        acc[m][n] = __builtin_amdgcn_mfma_f32_16x16x32_bf16(af[m], bg[n], acc[m][n], 0, 0, 0);
    if (t < kT - 1) {
      if (t + 2 < kT) { if (wu < 4) { WAITV(2); } else { WAITV(1); } }
      else            { WAITV(0); }
      BAR();
    }
  }

  int orow = (lane >> 4) * 4, ocol = lane & 15;
#pragma unroll
  for (int m = 0; m < 2; m++) {
    int gmb = m0 + wr * 32 + m * 16 + orow;
#pragma unroll
    for (int n = 0; n < 2; n++) {
      int gn = n0 + wc * 32 + n * 16 + ocol;
      if (gn < N) {
        float bv = bias[gn];
#pragma unroll
        for (int r = 0; r < 4; r++) {
          int gm = gmb + r;
          if (gm < M) C[(size_t)gm * N + gn] = f2bf(acc[m][n][r] + bv);
        }
      }
    }
  }
}

// ---------------- fused residual + LayerNorm (float4 vectorized) -------------
__global__ __launch_bounds__(256) void residual_ln_kernel(
    const float* __restrict__ vit, const unsigned short* __restrict__ attn,
    const float* __restrict__ gamma, const float* __restrict__ g,
    const float* __restrict__ b, float* __restrict__ vout,
    unsigned short* __restrict__ vln, int R) {
  int wid = blockIdx.x * 4 + (threadIdx.x >> 6);
  int lane = threadIdx.x & 63;
  if (wid >= R) return;
  const float4* ra = (const float4*)(vit + (size_t)wid * 768);
  const ushort4* rb = (const ushort4*)(attn + (size_t)wid * 768);
  float4* vo = (float4*)(vout + (size_t)wid * 768);
  ushort4* vl = (ushort4*)(vln + (size_t)wid * 768);
  float x[12]; float s = 0.f;
#pragma unroll
  for (int j = 0; j < 3; j++) {
    int c4 = lane + j * 64;
    float4 a = ra[c4];
    ushort4 t = rb[c4];
    float4 gm = ((const float4*)gamma)[c4];
    x[j*4+0] = a.x + gm.x * bf2f(t.x);
    x[j*4+1] = a.y + gm.y * bf2f(t.y);
    x[j*4+2] = a.z + gm.z * bf2f(t.z);
    x[j*4+3] = a.w + gm.w * bf2f(t.w);
    float4 o; o.x = x[j*4+0]; o.y = x[j*4+1]; o.z = x[j*4+2]; o.w = x[j*4+3];
    vo[c4] = o;
    s += x[j*4+0] + x[j*4+1] + x[j*4+2] + x[j*4+3];
  }
#pragma unroll
  for (int o = 32; o >= 1; o >>= 1) s += __shfl_xor(s, o);
  float mean = s * (1.f / 768.f);
  float v = 0.f;
#pragma unroll
  for (int j = 0; j < 12; j++) { float d = x[j] - mean; v += d * d; }
#pragma unroll
  for (int o = 32; o >= 1; o >>= 1) v += __shfl_xor(v, o);
  float rs = rsqrtf(v * (1.f / 768.f) + 1e-6f);
#pragma unroll
  for (int j = 0; j < 3; j++) {
    int c4 = lane + j * 64;
    float4 gg = ((const float4*)g)[c4];
    float4 bb = ((const float4*)b)[c4];
    ushort4 o;
    o.x = f2bf((x[j*4+0] - mean) * rs * gg.x + bb.x);
    o.y = f2bf((x[j*4+1] - mean) * rs * gg.y + bb.y);
    o.z = f2bf((x[j*4+2] - mean) * rs * gg.z + bb.z);
    o.w = f2bf((x[j*4+3] - mean) * rs * gg.w + bb.w);
    vl[c4] = o;
  }
}

// ---------------- add + LayerNorm -> f32 out (both inputs bf16) --------------
__global__ __launch_bounds__(256) void add_ln_f32_kernel(
    const unsigned short* __restrict__ Xa, const unsigned short* __restrict__ Xb,
    const float* __restrict__ g, const float* __restrict__ b,
    float* __restrict__ out, int R) {
  int wid = blockIdx.x * 4 + (threadIdx.x >> 6);
  int lane = threadIdx.x & 63;
  if (wid >= R) return;
  const ushort4* ra = (const ushort4*)(Xa + (size_t)wid * 768);
  const ushort4* rb = (const ushort4*)(Xb + (size_t)wid * 768);
  float4* ro = (float4*)(out + (size_t)wid * 768);
  float x[12]; float s = 0.f;
#pragma unroll
  for (int j = 0; j < 3; j++) {
    int c4 = lane + j * 64;
    ushort4 a = ra[c4];
    ushort4 t = rb[c4];
    x[j*4+0] = bf2f(a.x) + bf2f(t.x);
    x[j*4+1] = bf2f(a.y) + bf2f(t.y);
    x[j*4+2] = bf2f(a.z) + bf2f(t.z);
    x[j*4+3] = bf2f(a.w) + bf2f(t.w);
    s += x[j*4+0] + x[j*4+1] + x[j*4+2] + x[j*4+3];
  }
#pragma unroll
  for (int o = 32; o >= 1; o >>= 1) s += __shfl_xor(s, o);
  float mean = s * (1.f / 768.f);
  float v = 0.f;
#pragma unroll
  for (int j = 0; j < 12; j++) { float d = x[j] - mean; v += d * d; }
#pragma unroll
  for (int o = 32; o >= 1; o >>= 1) v += __shfl_xor(v, o);
  float rs = rsqrtf(v * (1.f / 768.f) + 1e-6f);
#pragma unroll
  for (int j = 0; j < 3; j++) {
    int c4 = lane + j * 64;
    float4 gg = ((const float4*)g)[c4];
    float4 bb = ((const float4*)b)[c4];
    float4 o;
    o.x = (x[j*4+0] - mean) * rs * gg.x + bb.x;
    o.y = (x[j*4+1] - mean) * rs * gg.y + bb.y;
    o.z = (x[j*4+2] - mean) * rs * gg.z + bb.z;
    o.w = (x[j*4+3] - mean) * rs * gg.w + bb.w;
    ro[c4] = o;
  }
}

// ---------------- deformable samplers: 8 ch/lane, 4 heads/wave ---------------
__global__ __launch_bounds__(256) void sampler_inj_kernel(
    const float* __restrict__ ref, const unsigned short* __restrict__ sa,
    const unsigned short* __restrict__ v, unsigned short* __restrict__ out, int vst) {
  int gw = (blockIdx.x * 256 + threadIdx.x) >> 6;
  int lane = threadIdx.x & 63;
  int qp = gw / 3, wv = gw - qp * 3;
  int gh = wv * 4 + (lane >> 4);
  int q = qp * 2 + (gh >= 6 ? 1 : 0);
  if (q >= LQ_VIT) return;
  int h = gh >= 6 ? gh - 6 : gh;
  int c = h * 128 + (lane & 15) * 8;
  float rx = ref[q * 2], ry = ref[q * 2 + 1];
  const unsigned short* row = sa + (size_t)q * 216;
  float lg[12]; float mx = -1e30f;
#pragma unroll
  for (int i = 0; i < 12; i++) { lg[i] = bf2f(row[144 + h * 12 + i]); mx = fmaxf(mx, lg[i]); }
  float s = 0.f;
#pragma unroll
  for (int i = 0; i < 12; i++) { lg[i] = __expf(lg[i] - mx); s += lg[i]; }
  float inv = 1.f / s;
  f32x8 acc = {};
  const int LW[3] = {96, 48, 24};
  const int LS[3] = {0, 9216, 11520};
#pragma unroll
  for (int l = 0; l < 3; l++) {
    const int Wl = LW[l], st = LS[l], Wm = Wl - 1;
    const float Wf = (float)Wl;
#pragma unroll
    for (int p = 0; p < 4; p++) {
      int ob = ((h * 3 + l) * 4 + p) * 2;
      float ix = fmaf(rx, Wf, bf2f(row[ob])) - 0.5f;
      float iy = fmaf(ry, Wf, bf2f(row[ob + 1])) - 0.5f;
      float x0f = floorf(ix), y0f = floorf(iy);
      float wx = ix - x0f, wy = iy - y0f;
      int x0 = (int)x0f, y0 = (int)y0f;
      float aw = lg[l * 4 + p] * inv;
      float wy0 = (1.f - wy) * aw, wy1 = wy * aw;
      float w00 = (1.f - wx) * wy0, w01 = wx * wy0;
      float w10 = (1.f - wx) * wy1, w11 = wx * wy1;
      bool xv0 = (unsigned)x0 < (unsigned)Wl, xv1 = (unsigned)(x0 + 1) < (unsigned)Wl;
      bool yv0 = (unsigned)y0 < (unsigned)Wl, yv1 = (unsigned)(y0 + 1) < (unsigned)Wl;
      w00 = (xv0 && yv0) ? w00 : 0.f;
      w01 = (xv1 && yv0) ? w01 : 0.f;
      w10 = (xv0 && yv1) ? w10 : 0.f;
      w11 = (xv1 && yv1) ? w11 : 0.f;
      int x0c = min(max(x0, 0), Wm), x1c = min(max(x0 + 1, 0), Wm);
      int y0c = min(max(y0, 0), Wm), y1c = min(max(y0 + 1, 0), Wm);
      const unsigned short* r0 = v + ((size_t)(st + y0c * Wl) * vst + c);
      const unsigned short* r1 = v + ((size_t)(st + y1c * Wl) * vst + c);
      acc += w00 * ld8bf(r0 + (size_t)x0c * vst) + w01 * ld8bf(r0 + (size_t)x1c * vst)
           + w10 * ld8bf(r1 + (size_t)x0c * vst) + w11 * ld8bf(r1 + (size_t)x1c * vst);
    }
  }
  u16x8 o8;
#pragma unroll
  for (int j = 0; j < 8; j++) o8[j] = f2bf(acc[j]);
  *(u16x8*)&out[(size_t)q * 768 + c] = o8;
}

__global__ __launch_bounds__(256) void sampler_ext_kernel(
    const float* __restrict__ ref, const unsigned short* __restrict__ sa, int sst,
    const unsigned short* __restrict__ v, unsigned short* __restrict__ out) {
  int gw = (blockIdx.x * 256 + threadIdx.x) >> 6;
  int lane = threadIdx.x & 63;
  int qp = gw / 3, wv = gw - qp * 3;
  int gh = wv * 4 + (lane >> 4);
  int q = qp * 2 + (gh >= 6 ? 1 : 0);
  if (q >= NA_ADA) return;
  int h = gh >= 6 ? gh - 6 : gh;
  int c = h * 128 + (lane & 15) * 8;
  float rx = ref[q * 2], ry = ref[q * 2 + 1];
  const unsigned short* row = sa + (size_t)q * sst;
  float lg[4]; float mx = -1e30f;
#pragma unroll
  for (int p = 0; p < 4; p++) { lg[p] = bf2f(row[48 + h * 4 + p]); mx = fmaxf(mx, lg[p]); }
  float s = 0.f;
#pragma unroll
  for (int p = 0; p < 4; p++) { lg[p] = __expf(lg[p] - mx); s += lg[p]; }
  float inv = 1.f / s;
  f32x8 acc = {};
#pragma unroll
  for (int p = 0; p < 4; p++) {
    int ob = (h * 4 + p) * 2;
    float ix = fmaf(rx, 48.f, bf2f(row[ob])) - 0.5f;
    float iy = fmaf(ry, 48.f, bf2f(row[ob + 1])) - 0.5f;
    float x0f = floorf(ix), y0f = floorf(iy);
    float wx = ix - x0f, wy = iy - y0f;
    int x0 = (int)x0f, y0 = (int)y0f;
    float aw = lg[p] * inv;
    float wy0 = (1.f - wy) * aw, wy1 = wy * aw;
    float w00 = (1.f - wx) * wy0, w01 = wx * wy0;
    float w10 = (1.f - wx) * wy1, w11 = wx * wy1;
    bool xv0 = (unsigned)x0 < 48u, xv1 = (unsigned)(x0 + 1) < 48u;
    bool yv0 = (unsigned)y0 < 48u, yv1 = (unsigned)(y0 + 1) < 48u;
    w00 = (xv0 && yv0) ? w00 : 0.f;
    w01 = (xv1 && yv0) ? w01 : 0.f;
    w10 = (xv0 && yv1) ? w10 : 0.f;
    w11 = (xv1 && yv1) ? w11 : 0.f;
    int x0c = min(max(x0, 0), 47), x1c = min(max(x0 + 1, 0), 47);
    int y0c = min(max(y0, 0), 47), y1c = min(max(y0 + 1, 0), 47);
    const unsigned short* r0 = v + ((size_t)(y0c * 48) * 768 + c);
    const unsigned short* r1 = v + ((size_t)(y1c * 48) * 768 + c);
    acc += w00 * ld8bf(r0 + (size_t)x0c * 768) + w01 * ld8bf(r0 + (size_t)x1c * 768)
         + w10 * ld8bf(r1 + (size_t)x0c * 768) + w11 * ld8bf(r1 + (size_t)x1c * 768);
  }
  u16x8 o8;
#pragma unroll
  for (int j = 0; j < 8; j++) o8[j] = f2bf(acc[j]);
  *(u16x8*)&out[(size_t)q * 768 + c] = o8;
}

extern "C" void kernel_launch(void* const* d_in, const int* in_sizes, int n_in,
                              void* d_out, int out_size, void* d_ws, size_t ws_size,
                              hipStream_t stream) {
  (void)in_sizes; (void)n_in; (void)out_size; (void)ws_size;
  const float* vit      = (const float*)d_in[0];
  const float* adapter  = (const float*)d_in[1];
  const float* ref1     = (const float*)d_in[2];
  const float* ref2     = (const float*)d_in[3];
  const float* inj_qn_g = (const float*)d_in[4];
  const float* inj_qn_b = (const float*)d_in[5];
  const float* inj_Wv   = (const float*)d_in[6];
  const float* inj_bv   = (const float*)d_in[7];
  const float* inj_Ws   = (const float*)d_in[8];
  const float* inj_bs   = (const float*)d_in[9];
  const float* inj_Wa   = (const float*)d_in[10];
  const float* inj_ba   = (const float*)d_in[11];
  const float* inj_Wo   = (const float*)d_in[12];
  const float* inj_bo   = (const float*)d_in[13];
  const float* inj_gamma= (const float*)d_in[14];
  const float* ext_vn_g = (const float*)d_in[15];
  const float* ext_vn_b = (const float*)d_in[16];
  const float* ext_qn_g = (const float*)d_in[17];
  const float* ext_qn_b = (const float*)d_in[18];
  const float* ext_Wv   = (const float*)d_in[19];
  const float* ext_bv   = (const float*)d_in[20];
  const float* ext_Ws   = (const float*)d_in[21];
  const float* ext_bs   = (const float*)d_in[22];
  const float* ext_Wa   = (const float*)d_in[23];
  const float* ext_ba   = (const float*)d_in[24];
  const float* ext_Wo   = (const float*)d_in[25];
  const float* ext_bo   = (const float*)d_in[26];

  size_t cur = 0;
  auto take = [&](size_t bytes) {
    void* p = (char*)d_ws + cur;
    cur += (bytes + 255) & ~(size_t)255;
    return p;
  };
  unsigned short* WBIG = (unsigned short*)take((size_t)840 * 768 * 2);
  unsigned short* WTIO = (unsigned short*)take((size_t)768 * 768 * 2);
  unsigned short* WTEV = (unsigned short*)take((size_t)768 * 768 * 2);
  unsigned short* WTEO = (unsigned short*)take((size_t)768 * 768 * 2);
  unsigned short* WSAI = (unsigned short*)take((size_t)216 * 768 * 2);
  float* BCI  = (float*)take((size_t)216 * 4);
  float* BBIG = (float*)take((size_t)840 * 4);
  unsigned short* ADBF = (unsigned short*)take((size_t)NA_ADA * 768 * 2);
  unsigned short* QLN  = (unsigned short*)take((size_t)LQ_VIT * 768 * 2);
  unsigned short* CBIG = (unsigned short*)take((size_t)NA_ADA * 840 * 2);  // [v_inj | sae]
  unsigned short* SAI  = (unsigned short*)take((size_t)LQ_VIT * 216 * 2);
  unsigned short* SAMPI= (unsigned short*)take((size_t)LQ_VIT * 768 * 2);
  unsigned short* ATTNI= (unsigned short*)take((size_t)LQ_VIT * 768 * 2);
  unsigned short* VLN  = (unsigned short*)take((size_t)LQ_VIT * 768 * 2);
  unsigned short* VEXT = (unsigned short*)take((size_t)LQ_VIT * 768 * 2);
  unsigned short* SAMPE= (unsigned short*)take((size_t)NA_ADA * 768 * 2);  // own buffer:
  unsigned short* ATTN2 = CBIG;   // ADBF stays live for add_ln (bf16 adapter)

  float* out_vit = (float*)d_out;
  float* out_ada = out_vit + (size_t)LQ_VIT * 768;

  PrepPack pp;
  pp.W[0] = inj_Wv; pp.WT[0] = WBIG;               pp.N[0] = 768;
  pp.W[1] = ext_Ws; pp.WT[1] = WBIG + 768 * 768;   pp.N[1] = 48;
  pp.W[2] = ext_Wa; pp.WT[2] = WBIG + 816 * 768;   pp.N[2] = 24;
  pp.W[3] = inj_Wo; pp.WT[3] = WTIO;               pp.N[3] = 768;
  pp.W[4] = ext_Wv; pp.WT[4] = WTEV;               pp.N[4] = 768;
  pp.W[5] = ext_Wo; pp.WT[5] = WTEO;               pp.N[5] = 768;
  pp.W[6] = inj_Ws; pp.WT[6] = WSAI;               pp.N[6] = 144;
  pp.W[7] = inj_Wa; pp.WT[7] = WSAI + 144 * 768;   pp.N[7] = 72;
  int cum = 0;
  for (int i = 0; i < 8; i++) { pp.cum[i] = cum; cum += (pp.N[i] + 31) / 32; }
  pp.cum[8] = cum;  // 107
  pp.adapter = adapter; pp.adbf = ADBF; pp.n4 = (NA_ADA * 768) / 4;
  pp.vit = vit; pp.qg = inj_qn_g; pp.qb = inj_qn_b; pp.qln = QLN;
  pp.isv = inj_bs; pp.iav = inj_ba; pp.ibv = inj_bv;
  pp.esv = ext_bs; pp.eav = ext_ba;
  pp.bci = BCI; pp.bbig = BBIG;
  prep_kernel<<<5193, 256, 0, stream>>>(pp);

  // launch 2: big GEMM 1 (N=840) packed with SAI (N=216), 8-wave
  GemmTask tA, tB;
  tA.A = ADBF; tA.BT = WBIG; tA.bias = BBIG; tA.C = CBIG;
  tA.M = NA_ADA; tA.N = 840; tA.NT = 7; tA.nwg = 95 * 7;
  tB.A = QLN; tB.BT = WSAI; tB.bias = BCI; tB.C = SAI;
  tB.M = LQ_VIT; tB.N = 216; tB.NT = 2; tB.nwg = 18 * 2;
  gemm_big8_kernel<<<95 * 7 + 18 * 2, 512, 0, stream>>>(tA, tB, 95 * 7);

  sampler_inj_kernel<<<864, 256, 0, stream>>>(ref1, SAI, CBIG, SAMPI, 840);

  gemm_mid8_kernel<<<36 * 6, 512, 0, stream>>>(SAMPI, WTIO, inj_bo, ATTNI, LQ_VIT, 768, 6);
  residual_ln_kernel<<<576, 256, 0, stream>>>(vit, ATTNI, inj_gamma, ext_vn_g, ext_vn_b,
                                              out_vit, VLN, LQ_VIT);
  gemm_mid8_kernel<<<36 * 6, 512, 0, stream>>>(VLN, WTEV, ext_bv, VEXT, LQ_VIT, 768, 6);

  sampler_ext_kernel<<<4536, 256, 0, stream>>>(ref2, CBIG + 768, 840, VEXT, SAMPE);

  // big GEMM 2 (N=768), 8-wave
  GemmTask tC;
  tC.A = SAMPE; tC.BT = WTEO; tC.bias = ext_bo; tC.C = ATTN2;
  tC.M = NA_ADA; tC.N = 768; tC.NT = 6; tC.nwg = 95 * 6;
  gemm_big8_kernel<<<95 * 6, 512, 0, stream>>>(tC, tC, 95 * 6);

  add_ln_f32_kernel<<<3024, 256, 0, stream>>>(ADBF, ATTN2, ext_qn_g, ext_qn_b, out_ada, NA_ADA);
}